// Round 1
// baseline (214.272 us; speedup 1.0000x reference)
//
#include <hip/hip_runtime.h>
#include <hip/hip_bf16.h>
#include <stdint.h>

#define SEQ   2048
#define NHEAD 32
#define HDIM  128
#define RS    (NHEAD * HDIM)   // 4096 floats: row stride in (b,s,h,d) layout
#define QBLK  64
#define KVBLK 64

typedef float  f32x4  __attribute__((ext_vector_type(4)));
typedef __bf16 bf16x8 __attribute__((ext_vector_type(8)));

__device__ __forceinline__ unsigned short f2bf(float f) {
  unsigned u = __builtin_bit_cast(unsigned, f);
  u += 0x7fffu + ((u >> 16) & 1u);           // round-to-nearest-even
  return (unsigned short)(u >> 16);
}

__global__ __launch_bounds__(256) void
fattn_kernel(const float* __restrict__ Q, const float* __restrict__ K,
             const float* __restrict__ V, float* __restrict__ O) {
  const int tid  = threadIdx.x;
  const int w    = tid >> 6;       // wave 0..3
  const int lane = tid & 63;
  const int lq   = lane & 15;
  const int lg   = lane >> 4;      // 0..3

  // bijective XCD swizzle (1024 blocks % 8 == 0): each XCD gets 4 whole heads
  const int bid = blockIdx.x;
  const int vid = (bid & 7) * 128 + (bid >> 3);
  const int h   = vid >> 5;                    // 0..31
  const int q0  = (31 - (vid & 31)) * QBLK;    // biggest-work q-blocks first

  __shared__ __align__(16) char smem[40960];
  char* Ksm = smem;                  // [64][128] bf16, XOR-swizzled
  char* Vsm = smem + 16384;          // transposed [128][64] bf16, XOR-swizzled
  char* Psm = smem + 32768 + (w << 11);  // per-wave [16][64] bf16

  // fold 1/sqrt(D) * log2(e) into Q so softmax uses exp2
  const float qscale = 0.088388347648318447f * 1.4426950408889634f;

  // Q fragments (A operand): lane holds Q[q0+w*16+lq][ks*32 + lg*8 + j]
  bf16x8 aq[4];
  {
    const int qrow = q0 + w * 16 + lq;
    const float* qp = Q + qrow * RS + h * HDIM + lg * 8;
#pragma unroll
    for (int ks = 0; ks < 4; ++ks) {
      float4 v0 = *(const float4*)(qp + ks * 32);
      float4 v1 = *(const float4*)(qp + ks * 32 + 4);
      bf16x8 a;
      a[0] = (__bf16)(v0.x * qscale); a[1] = (__bf16)(v0.y * qscale);
      a[2] = (__bf16)(v0.z * qscale); a[3] = (__bf16)(v0.w * qscale);
      a[4] = (__bf16)(v1.x * qscale); a[5] = (__bf16)(v1.y * qscale);
      a[6] = (__bf16)(v1.z * qscale); a[7] = (__bf16)(v1.w * qscale);
      aq[ks] = a;
    }
  }

  f32x4 accO[8];
#pragma unroll
  for (int i = 0; i < 8; ++i) accO[i] = (f32x4){0.f, 0.f, 0.f, 0.f};
  float m_run[4] = {-1e30f, -1e30f, -1e30f, -1e30f};
  float l_run[4] = {0.f, 0.f, 0.f, 0.f};

  const int qrow_base = q0 + w * 16 + lg * 4;   // acc row r = lg*4 + j

  for (int kv0 = 0; kv0 <= q0; kv0 += KVBLK) {
    // ---- stage K tile (row-major, swizzled) ----
    {
      const int c  = tid & 15;    // d-chunk (8 floats)
      const int kr = tid >> 4;    // 0..15
#pragma unroll
      for (int ki = 0; ki < 4; ++ki) {
        const int kk = kr + ki * 16;
        const float* kp = K + (kv0 + kk) * RS + h * HDIM + c * 8;
        float4 x0 = *(const float4*)kp;
        float4 x1 = *(const float4*)(kp + 4);
        uint32_t u0 = f2bf(x0.x) | ((uint32_t)f2bf(x0.y) << 16);
        uint32_t u1 = f2bf(x0.z) | ((uint32_t)f2bf(x0.w) << 16);
        uint32_t u2 = f2bf(x1.x) | ((uint32_t)f2bf(x1.y) << 16);
        uint32_t u3 = f2bf(x1.z) | ((uint32_t)f2bf(x1.w) << 16);
        const uint32_t byte = (uint32_t)(kk * 256 + c * 16) ^ (uint32_t)((kk & 7) << 4);
        *(uint4*)(Ksm + byte) = make_uint4(u0, u1, u2, u3);
      }
    }
    // ---- stage V tile transposed: Vt[d][k] (swizzled) ----
    {
      const int kk = (tid & 31) * 2;    // even k; handles rows kk, kk+1
      const int db = (tid >> 5) * 8;
#pragma unroll
      for (int p = 0; p < 2; ++p) {
        const int d0 = db + 64 * p;
        const float* vp = V + (kv0 + kk) * RS + h * HDIM + d0;
        float4 x0 = *(const float4*)(vp);
        float4 x1 = *(const float4*)(vp + 4);
        float4 y0 = *(const float4*)(vp + RS);
        float4 y1 = *(const float4*)(vp + RS + 4);
        float xs[8] = {x0.x, x0.y, x0.z, x0.w, x1.x, x1.y, x1.z, x1.w};
        float ys[8] = {y0.x, y0.y, y0.z, y0.w, y1.x, y1.y, y1.z, y1.w};
#pragma unroll
        for (int i = 0; i < 8; ++i) {
          const int d = d0 + i;
          const uint32_t val = f2bf(xs[i]) | ((uint32_t)f2bf(ys[i]) << 16);
          const uint32_t byte = (uint32_t)(d * 128 + kk * 2) ^ (uint32_t)((d & 7) << 4);
          *(uint32_t*)(Vsm + byte) = val;
        }
      }
    }
    __syncthreads();

    // ---- S = Q K^T : accS[nt][j] = S[lg*4+j][nt*16+lq] ----
    f32x4 accS[4];
#pragma unroll
    for (int nt = 0; nt < 4; ++nt) {
      f32x4 s = (f32x4){0.f, 0.f, 0.f, 0.f};
      const int krow = nt * 16 + lq;
#pragma unroll
      for (int ks = 0; ks < 4; ++ks) {
        const uint32_t byte = (uint32_t)(krow * 256 + ks * 64 + lg * 16) ^
                              (uint32_t)((krow & 7) << 4);
        bf16x8 bk = *(const bf16x8*)(Ksm + byte);
        s = __builtin_amdgcn_mfma_f32_16x16x32_bf16(aq[ks], bk, s, 0, 0, 0);
      }
      accS[nt] = s;
    }

    // ---- causal mask + online softmax (log2 domain) ----
    float mloc[4] = {-1e30f, -1e30f, -1e30f, -1e30f};
#pragma unroll
    for (int nt = 0; nt < 4; ++nt) {
      const int keyg = kv0 + nt * 16 + lq;
#pragma unroll
      for (int j = 0; j < 4; ++j) {
        float s = accS[nt][j];
        s = (keyg <= qrow_base + j) ? s : -1e30f;
        accS[nt][j] = s;
        mloc[j] = fmaxf(mloc[j], s);
      }
    }
#pragma unroll
    for (int off = 1; off < 16; off <<= 1) {
#pragma unroll
      for (int j = 0; j < 4; ++j)
        mloc[j] = fmaxf(mloc[j], __shfl_xor(mloc[j], off, 64));
    }
    float alpha[4];
#pragma unroll
    for (int j = 0; j < 4; ++j) {
      const float mn = fmaxf(m_run[j], mloc[j]);
      alpha[j] = exp2f(m_run[j] - mn);
      m_run[j] = mn;
    }
    float rsum[4] = {0.f, 0.f, 0.f, 0.f};
#pragma unroll
    for (int nt = 0; nt < 4; ++nt) {
#pragma unroll
      for (int j = 0; j < 4; ++j) {
        const float p = exp2f(accS[nt][j] - m_run[j]);
        accS[nt][j] = p;
        rsum[j] += p;
      }
    }
#pragma unroll
    for (int off = 1; off < 16; off <<= 1) {
#pragma unroll
      for (int j = 0; j < 4; ++j) rsum[j] += __shfl_xor(rsum[j], off, 64);
    }
#pragma unroll
    for (int j = 0; j < 4; ++j) l_run[j] = l_run[j] * alpha[j] + rsum[j];
#pragma unroll
    for (int dt = 0; dt < 8; ++dt) {
#pragma unroll
      for (int j = 0; j < 4; ++j) accO[dt][j] *= alpha[j];
    }

    // ---- P -> LDS (wave-private region, swizzled) ----
#pragma unroll
    for (int j = 0; j < 4; ++j) {
      const int r = lg * 4 + j;
#pragma unroll
      for (int nt = 0; nt < 4; ++nt) {
        const int col = nt * 16 + lq;
        const uint32_t byte = (uint32_t)(r * 128 + col * 2) ^ (uint32_t)((r & 7) << 4);
        *(uint16_t*)(Psm + byte) = f2bf(accS[nt][j]);
      }
    }
    __syncthreads();   // orders P writes vs cross-lane P reads (and TBAA-safe)

    // ---- O += P V ----
#pragma unroll
    for (int ks2 = 0; ks2 < 2; ++ks2) {
      const uint32_t ab = (uint32_t)(lq * 128 + ks2 * 64 + lg * 16) ^
                          (uint32_t)((lq & 7) << 4);
      bf16x8 ap = *(const bf16x8*)(Psm + ab);
#pragma unroll
      for (int dt = 0; dt < 8; ++dt) {
        const int vrow = dt * 16 + lq;
        const uint32_t bb = (uint32_t)(vrow * 128 + ks2 * 64 + lg * 16) ^
                            (uint32_t)((vrow & 7) << 4);
        bf16x8 bv = *(const bf16x8*)(Vsm + bb);
        accO[dt] = __builtin_amdgcn_mfma_f32_16x16x32_bf16(ap, bv, accO[dt], 0, 0, 0);
      }
    }
    __syncthreads();   // protect K/V tiles before next staging
  }

  // ---- epilogue: O / l, f32 store ----
#pragma unroll
  for (int j = 0; j < 4; ++j) {
    const float inv = 1.0f / l_run[j];
    float* op = O + (qrow_base + j) * RS + h * HDIM + lq;
#pragma unroll
    for (int dt = 0; dt < 8; ++dt) op[dt * 16] = accO[dt][j] * inv;
  }
}

extern "C" void kernel_launch(void* const* d_in, const int* in_sizes, int n_in,
                              void* d_out, int out_size, void* d_ws, size_t ws_size,
                              hipStream_t stream) {
  const float* q = (const float*)d_in[0];
  const float* k = (const float*)d_in[1];
  const float* v = (const float*)d_in[2];
  float* o = (float*)d_out;
  dim3 grid(NHEAD * (SEQ / QBLK));  // 1024 blocks
  dim3 block(256);
  hipLaunchKernelGGL(fattn_kernel, grid, block, 0, stream, q, k, v, o);
}

// Round 2
// 158.154 us; speedup vs baseline: 1.3548x; 1.3548x over previous
//
#include <hip/hip_runtime.h>
#include <hip/hip_bf16.h>
#include <stdint.h>

#define SEQ   2048
#define NHEAD 32
#define HDIM  128
#define RS    (NHEAD * HDIM)   // 4096 floats: row stride in (b,s,h,d) layout
#define KVBLK 64
#define NTILES (SEQ / KVBLK)   // 32
#define TILE_BYTES 16384       // 64*128 bf16 = 16 KB per tile (K) / 128*64 (V^T)

typedef float  f32x4  __attribute__((ext_vector_type(4)));
typedef __bf16 bf16x8 __attribute__((ext_vector_type(8)));

__device__ __forceinline__ unsigned short f2bf(float f) {
  unsigned u = __builtin_bit_cast(unsigned, f);
  u += 0x7fffu + ((u >> 16) & 1u);           // round-to-nearest-even
  return (unsigned short)(u >> 16);
}

__device__ __forceinline__ void gld16(const void* g, void* l) {
  // async global->LDS, 16B/lane; LDS dest is wave-uniform base (HW adds lane*16)
  __builtin_amdgcn_global_load_lds(
      (const __attribute__((address_space(1))) unsigned int*)g,
      (__attribute__((address_space(3))) unsigned int*)l, 16, 0, 0);
}

// ---------------- pre-pass: K -> bf16 swizzled tiles, V -> bf16 transposed swizzled tiles ----
// wsK layout: [head][tile][16KB], byte image == main kernel's LDS K tile
// wsV layout: [head][tile][16KB], byte image == main kernel's LDS V^T tile
__global__ __launch_bounds__(256) void prepass_kernel(
    const float* __restrict__ K, const float* __restrict__ V,
    char* __restrict__ wsK, char* __restrict__ wsV) {
  const int tid = threadIdx.x;
  const int t   = blockIdx.x & (NTILES - 1);
  const int h   = blockIdx.x >> 5;
  const int kv0 = t * KVBLK;
  char* kd = wsK + (size_t)(h * NTILES + t) * TILE_BYTES;
  char* vd = wsV + (size_t)(h * NTILES + t) * TILE_BYTES;

  // K: [64][128] bf16, byte = (kk*256 + c*16) ^ ((kk&7)<<4)
  {
    const int c  = tid & 15;    // d-chunk of 8 floats
    const int kr = tid >> 4;    // 0..15
#pragma unroll
    for (int ki = 0; ki < 4; ++ki) {
      const int kk = kr + ki * 16;
      const float* kp = K + (size_t)(kv0 + kk) * RS + h * HDIM + c * 8;
      float4 x0 = *(const float4*)kp;
      float4 x1 = *(const float4*)(kp + 4);
      uint32_t u0 = f2bf(x0.x) | ((uint32_t)f2bf(x0.y) << 16);
      uint32_t u1 = f2bf(x0.z) | ((uint32_t)f2bf(x0.w) << 16);
      uint32_t u2 = f2bf(x1.x) | ((uint32_t)f2bf(x1.y) << 16);
      uint32_t u3 = f2bf(x1.z) | ((uint32_t)f2bf(x1.w) << 16);
      const uint32_t byte = (uint32_t)(kk * 256 + c * 16) ^ (uint32_t)((kk & 7) << 4);
      *(uint4*)(kd + byte) = make_uint4(u0, u1, u2, u3);
    }
  }
  // V^T: [128][64] bf16, byte = (d*128 + kk*2) ^ ((d&7)<<4); 16B chunk = 8 kk values
  if (tid < 128) {
    const int d0  = (tid & 15) * 8;   // 8 d values
    const int kk0 = (tid >> 4) * 8;   // 8 kk values
    float vv[8][8];
#pragma unroll
    for (int r = 0; r < 8; ++r) {
      const float* vp = V + (size_t)(kv0 + kk0 + r) * RS + h * HDIM + d0;
      float4 x0 = *(const float4*)vp;
      float4 x1 = *(const float4*)(vp + 4);
      vv[r][0] = x0.x; vv[r][1] = x0.y; vv[r][2] = x0.z; vv[r][3] = x0.w;
      vv[r][4] = x1.x; vv[r][5] = x1.y; vv[r][6] = x1.z; vv[r][7] = x1.w;
    }
#pragma unroll
    for (int i = 0; i < 8; ++i) {
      const int d = d0 + i;
      uint32_t p0 = f2bf(vv[0][i]) | ((uint32_t)f2bf(vv[1][i]) << 16);
      uint32_t p1 = f2bf(vv[2][i]) | ((uint32_t)f2bf(vv[3][i]) << 16);
      uint32_t p2 = f2bf(vv[4][i]) | ((uint32_t)f2bf(vv[5][i]) << 16);
      uint32_t p3 = f2bf(vv[6][i]) | ((uint32_t)f2bf(vv[7][i]) << 16);
      const uint32_t byte = (uint32_t)(d * 128 + kk0 * 2) ^ (uint32_t)((d & 7) << 4);
      *(uint4*)(vd + byte) = make_uint4(p0, p1, p2, p3);
    }
  }
}

// ---------------- main kernel: paired q-blocks (i, 31-i), dbuf K/V via global_load_lds ----
__global__ __launch_bounds__(256) void fattn_main(
    const float* __restrict__ Q, const char* __restrict__ wsK,
    const char* __restrict__ wsV, float* __restrict__ O) {
  const int tid  = threadIdx.x;
  const int w    = tid >> 6;
  const int lane = tid & 63;
  const int lq   = lane & 15;
  const int lg   = lane >> 4;

  // bijective XCD swizzle over 512 blocks: each XCD gets 64 consecutive vids = 4 heads
  const int bid   = blockIdx.x;
  const int vid   = (bid & 7) * 64 + (bid >> 3);
  const int head  = vid >> 4;
  const int pairi = vid & 15;

  __shared__ __align__(16) char smem[73728];
  char* KsmB = smem;                     // 2 x 16KB K tiles
  char* VsmB = smem + 32768;             // 2 x 16KB V^T tiles
  char* Psm  = smem + 65536 + (w << 11); // per-wave [16][64] bf16

  const float qscale = 0.088388347648318447f * 1.4426950408889634f; // 1/sqrt(D)*log2(e)

  const char* kbase = wsK + (size_t)head * NTILES * TILE_BYTES;
  const char* vbase = wsV + (size_t)head * NTILES * TILE_BYTES;
  const int   stoff = w * 4096 + lane * 16;   // per-lane global staging offset

  auto stage = [&](int buf, int t) {
    const char* gk = kbase + t * TILE_BYTES + stoff;
    const char* gv = vbase + t * TILE_BYTES + stoff;
    char* lk = KsmB + buf * TILE_BYTES + w * 4096;
    char* lv = VsmB + buf * TILE_BYTES + w * 4096;
#pragma unroll
    for (int i = 0; i < 4; ++i) {
      gld16(gk + i * 1024, lk + i * 1024);
      gld16(gv + i * 1024, lv + i * 1024);
    }
  };

  for (int pass = 0; pass < 2; ++pass) {
    const int qb    = pass ? (31 - pairi) : pairi;
    const int q0    = qb * KVBLK;
    const int ntile = qb + 1;

    // Q fragments: lane holds Q[q0+w*16+lq][ks*32 + lg*8 + j], scaled
    bf16x8 aq[4];
    {
      const int qrow = q0 + w * 16 + lq;
      const float* qp = Q + (size_t)qrow * RS + head * HDIM + lg * 8;
#pragma unroll
      for (int ks = 0; ks < 4; ++ks) {
        float4 v0 = *(const float4*)(qp + ks * 32);
        float4 v1 = *(const float4*)(qp + ks * 32 + 4);
        bf16x8 a;
        a[0] = (__bf16)(v0.x * qscale); a[1] = (__bf16)(v0.y * qscale);
        a[2] = (__bf16)(v0.z * qscale); a[3] = (__bf16)(v0.w * qscale);
        a[4] = (__bf16)(v1.x * qscale); a[5] = (__bf16)(v1.y * qscale);
        a[6] = (__bf16)(v1.z * qscale); a[7] = (__bf16)(v1.w * qscale);
        aq[ks] = a;
      }
    }

    f32x4 accO[8];
#pragma unroll
    for (int i = 0; i < 8; ++i) accO[i] = (f32x4){0.f, 0.f, 0.f, 0.f};
    float m_run[4] = {-1e30f, -1e30f, -1e30f, -1e30f};
    float l_run[4] = {0.f, 0.f, 0.f, 0.f};
    const int qrow_base = q0 + w * 16 + lg * 4;

    stage(0, 0);
    __syncthreads();

    for (int t = 0; t < ntile; ++t) {
      const int cur = t & 1;
      if (t + 1 < ntile) stage(cur ^ 1, t + 1);   // async prefetch next tile
      const char* Kc = KsmB + cur * TILE_BYTES;
      const char* Vc = VsmB + cur * TILE_BYTES;

      // ---- S = Q K^T ----
      f32x4 accS[4];
#pragma unroll
      for (int nt = 0; nt < 4; ++nt) {
        f32x4 s = (f32x4){0.f, 0.f, 0.f, 0.f};
        const int krow = nt * 16 + lq;
#pragma unroll
        for (int ks = 0; ks < 4; ++ks) {
          const uint32_t byte = (uint32_t)(krow * 256 + ks * 64 + lg * 16) ^
                                (uint32_t)((krow & 7) << 4);
          bf16x8 bk = *(const bf16x8*)(Kc + byte);
          s = __builtin_amdgcn_mfma_f32_16x16x32_bf16(aq[ks], bk, s, 0, 0, 0);
        }
        accS[nt] = s;
      }

      // ---- causal mask (diagonal tile only) + online softmax (log2 domain) ----
      float mloc[4] = {-1e30f, -1e30f, -1e30f, -1e30f};
      if (t == ntile - 1) {   // kv0 == q0: diagonal tile
        const int kv0 = t * KVBLK;
#pragma unroll
        for (int nt = 0; nt < 4; ++nt) {
          const int keyg = kv0 + nt * 16 + lq;
#pragma unroll
          for (int j = 0; j < 4; ++j) {
            float s = accS[nt][j];
            s = (keyg <= qrow_base + j) ? s : -1e30f;
            accS[nt][j] = s;
            mloc[j] = fmaxf(mloc[j], s);
          }
        }
      } else {
#pragma unroll
        for (int nt = 0; nt < 4; ++nt)
#pragma unroll
          for (int j = 0; j < 4; ++j) mloc[j] = fmaxf(mloc[j], accS[nt][j]);
      }
#pragma unroll
      for (int off = 1; off < 16; off <<= 1) {
#pragma unroll
        for (int j = 0; j < 4; ++j)
          mloc[j] = fmaxf(mloc[j], __shfl_xor(mloc[j], off, 64));
      }
      float alpha[4];
#pragma unroll
      for (int j = 0; j < 4; ++j) {
        const float mn = fmaxf(m_run[j], mloc[j]);
        alpha[j] = exp2f(m_run[j] - mn);
        m_run[j] = mn;
      }
      float rsum[4] = {0.f, 0.f, 0.f, 0.f};
#pragma unroll
      for (int nt = 0; nt < 4; ++nt) {
#pragma unroll
        for (int j = 0; j < 4; ++j) {
          const float p = exp2f(accS[nt][j] - m_run[j]);
          accS[nt][j] = p;
          rsum[j] += p;
        }
      }
#pragma unroll
      for (int off = 1; off < 16; off <<= 1) {
#pragma unroll
        for (int j = 0; j < 4; ++j) rsum[j] += __shfl_xor(rsum[j], off, 64);
      }
#pragma unroll
      for (int j = 0; j < 4; ++j) l_run[j] = l_run[j] * alpha[j] + rsum[j];
#pragma unroll
      for (int dt = 0; dt < 8; ++dt)
#pragma unroll
        for (int j = 0; j < 4; ++j) accO[dt][j] *= alpha[j];

      // ---- P -> wave-private LDS (DS ops are in-order per wave; fence stops reordering) ----
#pragma unroll
      for (int j = 0; j < 4; ++j) {
        const int r = lg * 4 + j;
#pragma unroll
        for (int nt = 0; nt < 4; ++nt) {
          const int col = nt * 16 + lq;
          const uint32_t byte = (uint32_t)(r * 128 + col * 2) ^ (uint32_t)((r & 7) << 4);
          *(uint16_t*)(Psm + byte) = f2bf(accS[nt][j]);
        }
      }
      asm volatile("" ::: "memory");

      // ---- O += P V ----
#pragma unroll
      for (int ks2 = 0; ks2 < 2; ++ks2) {
        const uint32_t ab = (uint32_t)(lq * 128 + ks2 * 64 + lg * 16) ^
                            (uint32_t)((lq & 7) << 4);
        bf16x8 ap = *(const bf16x8*)(Psm + ab);
#pragma unroll
        for (int dt = 0; dt < 8; ++dt) {
          const int vrow = dt * 16 + lq;
          const uint32_t bb = (uint32_t)(vrow * 128 + ks2 * 64 + lg * 16) ^
                              (uint32_t)((vrow & 7) << 4);
          bf16x8 bv = *(const bf16x8*)(Vc + bb);
          accO[dt] = __builtin_amdgcn_mfma_f32_16x16x32_bf16(ap, bv, accO[dt], 0, 0, 0);
        }
      }
      __syncthreads();   // drains vmcnt (prefetch landed) + protects tiles for next iter
    }

    // ---- epilogue ----
#pragma unroll
    for (int j = 0; j < 4; ++j) {
      const float inv = 1.0f / l_run[j];
      float* op = O + (size_t)(qrow_base + j) * RS + head * HDIM + lq;
#pragma unroll
      for (int dt = 0; dt < 8; ++dt) op[dt * 16] = accO[dt][j] * inv;
    }
  }
}

// ---------------- fallback (round-1 kernel, used if ws too small) ----------------
__global__ __launch_bounds__(256) void
fattn_fallback(const float* __restrict__ Q, const float* __restrict__ K,
               const float* __restrict__ V, float* __restrict__ O) {
  const int tid  = threadIdx.x;
  const int w    = tid >> 6;
  const int lane = tid & 63;
  const int lq   = lane & 15;
  const int lg   = lane >> 4;
  const int bid = blockIdx.x;
  const int vid = (bid & 7) * 128 + (bid >> 3);
  const int h   = vid >> 5;
  const int q0  = (31 - (vid & 31)) * KVBLK;

  __shared__ __align__(16) char smem[40960];
  char* Ksm = smem;
  char* Vsm = smem + 16384;
  char* Psm = smem + 32768 + (w << 11);
  const float qscale = 0.088388347648318447f * 1.4426950408889634f;

  bf16x8 aq[4];
  {
    const int qrow = q0 + w * 16 + lq;
    const float* qp = Q + (size_t)qrow * RS + h * HDIM + lg * 8;
#pragma unroll
    for (int ks = 0; ks < 4; ++ks) {
      float4 v0 = *(const float4*)(qp + ks * 32);
      float4 v1 = *(const float4*)(qp + ks * 32 + 4);
      bf16x8 a;
      a[0] = (__bf16)(v0.x * qscale); a[1] = (__bf16)(v0.y * qscale);
      a[2] = (__bf16)(v0.z * qscale); a[3] = (__bf16)(v0.w * qscale);
      a[4] = (__bf16)(v1.x * qscale); a[5] = (__bf16)(v1.y * qscale);
      a[6] = (__bf16)(v1.z * qscale); a[7] = (__bf16)(v1.w * qscale);
      aq[ks] = a;
    }
  }
  f32x4 accO[8];
#pragma unroll
  for (int i = 0; i < 8; ++i) accO[i] = (f32x4){0.f, 0.f, 0.f, 0.f};
  float m_run[4] = {-1e30f, -1e30f, -1e30f, -1e30f};
  float l_run[4] = {0.f, 0.f, 0.f, 0.f};
  const int qrow_base = q0 + w * 16 + lg * 4;

  for (int kv0 = 0; kv0 <= q0; kv0 += KVBLK) {
    {
      const int c  = tid & 15;
      const int kr = tid >> 4;
#pragma unroll
      for (int ki = 0; ki < 4; ++ki) {
        const int kk = kr + ki * 16;
        const float* kp = K + (size_t)(kv0 + kk) * RS + h * HDIM + c * 8;
        float4 x0 = *(const float4*)kp;
        float4 x1 = *(const float4*)(kp + 4);
        uint32_t u0 = f2bf(x0.x) | ((uint32_t)f2bf(x0.y) << 16);
        uint32_t u1 = f2bf(x0.z) | ((uint32_t)f2bf(x0.w) << 16);
        uint32_t u2 = f2bf(x1.x) | ((uint32_t)f2bf(x1.y) << 16);
        uint32_t u3 = f2bf(x1.z) | ((uint32_t)f2bf(x1.w) << 16);
        const uint32_t byte = (uint32_t)(kk * 256 + c * 16) ^ (uint32_t)((kk & 7) << 4);
        *(uint4*)(Ksm + byte) = make_uint4(u0, u1, u2, u3);
      }
    }
    {
      const int kk = (tid & 31) * 2;
      const int db = (tid >> 5) * 8;
#pragma unroll
      for (int p = 0; p < 2; ++p) {
        const int d0 = db + 64 * p;
        const float* vp = V + (size_t)(kv0 + kk) * RS + h * HDIM + d0;
        float4 x0 = *(const float4*)(vp);
        float4 x1 = *(const float4*)(vp + 4);
        float4 y0 = *(const float4*)(vp + RS);
        float4 y1 = *(const float4*)(vp + RS + 4);
        float xs[8] = {x0.x, x0.y, x0.z, x0.w, x1.x, x1.y, x1.z, x1.w};
        float ys[8] = {y0.x, y0.y, y0.z, y0.w, y1.x, y1.y, y1.z, y1.w};
#pragma unroll
        for (int i = 0; i < 8; ++i) {
          const int d = d0 + i;
          const uint32_t val = f2bf(xs[i]) | ((uint32_t)f2bf(ys[i]) << 16);
          const uint32_t byte = (uint32_t)(d * 128 + kk * 2) ^ (uint32_t)((d & 7) << 4);
          *(uint32_t*)(Vsm + byte) = val;
        }
      }
    }
    __syncthreads();

    f32x4 accS[4];
#pragma unroll
    for (int nt = 0; nt < 4; ++nt) {
      f32x4 s = (f32x4){0.f, 0.f, 0.f, 0.f};
      const int krow = nt * 16 + lq;
#pragma unroll
      for (int ks = 0; ks < 4; ++ks) {
        const uint32_t byte = (uint32_t)(krow * 256 + ks * 64 + lg * 16) ^
                              (uint32_t)((krow & 7) << 4);
        bf16x8 bk = *(const bf16x8*)(Ksm + byte);
        s = __builtin_amdgcn_mfma_f32_16x16x32_bf16(aq[ks], bk, s, 0, 0, 0);
      }
      accS[nt] = s;
    }
    float mloc[4] = {-1e30f, -1e30f, -1e30f, -1e30f};
#pragma unroll
    for (int nt = 0; nt < 4; ++nt) {
      const int keyg = kv0 + nt * 16 + lq;
#pragma unroll
      for (int j = 0; j < 4; ++j) {
        float s = accS[nt][j];
        s = (keyg <= qrow_base + j) ? s : -1e30f;
        accS[nt][j] = s;
        mloc[j] = fmaxf(mloc[j], s);
      }
    }
#pragma unroll
    for (int off = 1; off < 16; off <<= 1) {
#pragma unroll
      for (int j = 0; j < 4; ++j)
        mloc[j] = fmaxf(mloc[j], __shfl_xor(mloc[j], off, 64));
    }
    float alpha[4];
#pragma unroll
    for (int j = 0; j < 4; ++j) {
      const float mn = fmaxf(m_run[j], mloc[j]);
      alpha[j] = exp2f(m_run[j] - mn);
      m_run[j] = mn;
    }
    float rsum[4] = {0.f, 0.f, 0.f, 0.f};
#pragma unroll
    for (int nt = 0; nt < 4; ++nt) {
#pragma unroll
      for (int j = 0; j < 4; ++j) {
        const float p = exp2f(accS[nt][j] - m_run[j]);
        accS[nt][j] = p;
        rsum[j] += p;
      }
    }
#pragma unroll
    for (int off = 1; off < 16; off <<= 1) {
#pragma unroll
      for (int j = 0; j < 4; ++j) rsum[j] += __shfl_xor(rsum[j], off, 64);
    }
#pragma unroll
    for (int j = 0; j < 4; ++j) l_run[j] = l_run[j] * alpha[j] + rsum[j];
#pragma unroll
    for (int dt = 0; dt < 8; ++dt)
#pragma unroll
      for (int j = 0; j < 4; ++j) accO[dt][j] *= alpha[j];

#pragma unroll
    for (int j = 0; j < 4; ++j) {
      const int r = lg * 4 + j;
#pragma unroll
      for (int nt = 0; nt < 4; ++nt) {
        const int col = nt * 16 + lq;
        const uint32_t byte = (uint32_t)(r * 128 + col * 2) ^ (uint32_t)((r & 7) << 4);
        *(uint16_t*)(Psm + byte) = f2bf(accS[nt][j]);
      }
    }
    __syncthreads();

#pragma unroll
    for (int ks2 = 0; ks2 < 2; ++ks2) {
      const uint32_t ab = (uint32_t)(lq * 128 + ks2 * 64 + lg * 16) ^
                          (uint32_t)((lq & 7) << 4);
      bf16x8 ap = *(const bf16x8*)(Psm + ab);
#pragma unroll
      for (int dt = 0; dt < 8; ++dt) {
        const int vrow = dt * 16 + lq;
        const uint32_t bb = (uint32_t)(vrow * 128 + ks2 * 64 + lg * 16) ^
                            (uint32_t)((vrow & 7) << 4);
        bf16x8 bv = *(const bf16x8*)(Vsm + bb);
        accO[dt] = __builtin_amdgcn_mfma_f32_16x16x32_bf16(ap, bv, accO[dt], 0, 0, 0);
      }
    }
    __syncthreads();
  }
#pragma unroll
  for (int j = 0; j < 4; ++j) {
    const float inv = 1.0f / l_run[j];
    float* op = O + (size_t)(qrow_base + j) * RS + h * HDIM + lq;
#pragma unroll
    for (int dt = 0; dt < 8; ++dt) op[dt * 16] = accO[dt][j] * inv;
  }
}

extern "C" void kernel_launch(void* const* d_in, const int* in_sizes, int n_in,
                              void* d_out, int out_size, void* d_ws, size_t ws_size,
                              hipStream_t stream) {
  const float* q = (const float*)d_in[0];
  const float* k = (const float*)d_in[1];
  const float* v = (const float*)d_in[2];
  float* o = (float*)d_out;
  const size_t half = (size_t)NHEAD * NTILES * TILE_BYTES;   // 16.78 MB
  if (ws_size >= 2 * half) {
    char* wsK = (char*)d_ws;
    char* wsV = wsK + half;
    hipLaunchKernelGGL(prepass_kernel, dim3(NHEAD * NTILES), dim3(256), 0, stream,
                       k, v, wsK, wsV);
    hipLaunchKernelGGL(fattn_main, dim3(512), dim3(256), 0, stream, q, wsK, wsV, o);
  } else {
    hipLaunchKernelGGL(fattn_fallback, dim3(NHEAD * NTILES), dim3(256), 0, stream,
                       q, k, v, o);
  }
}

// Round 3
// 148.005 us; speedup vs baseline: 1.4477x; 1.0686x over previous
//
#include <hip/hip_runtime.h>
#include <hip/hip_bf16.h>
#include <stdint.h>

#define SEQ   2048
#define NHEAD 32
#define HDIM  128
#define RS    (NHEAD * HDIM)   // 4096 floats: row stride in (b,s,h,d) layout
#define KVBLK 64
#define QBLK  128
#define NTILES (SEQ / KVBLK)   // 32 kv tiles
#define TILE_BYTES 16384       // 64*128 bf16 per K tile / 128*64 per V^T tile

typedef float  f32x4  __attribute__((ext_vector_type(4)));
typedef __bf16 bf16x8 __attribute__((ext_vector_type(8)));

__device__ __forceinline__ unsigned short f2bf(float f) {
  unsigned u = __builtin_bit_cast(unsigned, f);
  u += 0x7fffu + ((u >> 16) & 1u);           // round-to-nearest-even
  return (unsigned short)(u >> 16);
}

__device__ __forceinline__ void gld16(const void* g, void* l) {
  // async global->LDS, 16B/lane; LDS dest is wave-uniform base (HW adds lane*16)
  __builtin_amdgcn_global_load_lds(
      (const __attribute__((address_space(1))) unsigned int*)g,
      (__attribute__((address_space(3))) unsigned int*)l, 16, 0, 0);
}

// ---------------- pre-pass: K -> bf16 swizzled tiles, V -> bf16 transposed swizzled tiles ----
__global__ __launch_bounds__(256) void prepass_kernel(
    const float* __restrict__ K, const float* __restrict__ V,
    char* __restrict__ wsK, char* __restrict__ wsV) {
  const int tid = threadIdx.x;
  const int t   = blockIdx.x & (NTILES - 1);
  const int h   = blockIdx.x >> 5;
  const int kv0 = t * KVBLK;
  char* kd = wsK + (size_t)(h * NTILES + t) * TILE_BYTES;
  char* vd = wsV + (size_t)(h * NTILES + t) * TILE_BYTES;

  // K: [64][128] bf16, byte = (kk*256 + c*16) ^ ((kk&7)<<4)
  {
    const int c  = tid & 15;    // d-chunk of 8 floats
    const int kr = tid >> 4;    // 0..15
#pragma unroll
    for (int ki = 0; ki < 4; ++ki) {
      const int kk = kr + ki * 16;
      const float* kp = K + (size_t)(kv0 + kk) * RS + h * HDIM + c * 8;
      float4 x0 = *(const float4*)kp;
      float4 x1 = *(const float4*)(kp + 4);
      uint32_t u0 = f2bf(x0.x) | ((uint32_t)f2bf(x0.y) << 16);
      uint32_t u1 = f2bf(x0.z) | ((uint32_t)f2bf(x0.w) << 16);
      uint32_t u2 = f2bf(x1.x) | ((uint32_t)f2bf(x1.y) << 16);
      uint32_t u3 = f2bf(x1.z) | ((uint32_t)f2bf(x1.w) << 16);
      const uint32_t byte = (uint32_t)(kk * 256 + c * 16) ^ (uint32_t)((kk & 7) << 4);
      *(uint4*)(kd + byte) = make_uint4(u0, u1, u2, u3);
    }
  }
  // V^T: [128][64] bf16, byte = (d*128 + kk*2) ^ ((d&7)<<4); all 256 threads
  {
    const int d0  = (tid & 31) * 4;   // 4 d values
    const int kk0 = (tid >> 5) * 8;   // 8 kk values
    float vv[8][4];
#pragma unroll
    for (int r = 0; r < 8; ++r) {
      const float* vp = V + (size_t)(kv0 + kk0 + r) * RS + h * HDIM + d0;
      float4 x = *(const float4*)vp;
      vv[r][0] = x.x; vv[r][1] = x.y; vv[r][2] = x.z; vv[r][3] = x.w;
    }
#pragma unroll
    for (int i = 0; i < 4; ++i) {
      const int d = d0 + i;
      uint32_t p0 = f2bf(vv[0][i]) | ((uint32_t)f2bf(vv[1][i]) << 16);
      uint32_t p1 = f2bf(vv[2][i]) | ((uint32_t)f2bf(vv[3][i]) << 16);
      uint32_t p2 = f2bf(vv[4][i]) | ((uint32_t)f2bf(vv[5][i]) << 16);
      uint32_t p3 = f2bf(vv[6][i]) | ((uint32_t)f2bf(vv[7][i]) << 16);
      const uint32_t byte = (uint32_t)(d * 128 + kk0 * 2) ^ (uint32_t)((d & 7) << 4);
      *(uint4*)(vd + byte) = make_uint4(p0, p1, p2, p3);
    }
  }
}

// ---------------- main kernel: QBLK=128, 8 waves, single-buffer K/V, complement-paired grid ----
__global__ __launch_bounds__(512, 4) void fattn_main(
    const float* __restrict__ Q, const char* __restrict__ wsK,
    const char* __restrict__ wsV, float* __restrict__ O) {
  const int tid  = threadIdx.x;
  const int w    = tid >> 6;      // wave 0..7
  const int lane = tid & 63;
  const int lq   = lane & 15;
  const int lg   = lane >> 4;

  // XCD swizzle + complement pairing: breadth-first dispatch puts (bid, bid+256)
  // on the same CU; their qb values sum to 15 -> exactly 34 tile-iters per CU.
  const int bid  = blockIdx.x;          // 0..511
  const int b2   = bid & 255;
  const int vid  = (b2 & 7) * 32 + (b2 >> 3);   // XCD x gets heads 4x..4x+3
  const int head = vid >> 3;
  const int jj   = vid & 7;
  const int qb   = (bid < 256) ? (15 - jj) : jj;
  const int q0   = qb * QBLK;
  const int ntile  = 2 * qb + 2;
  const int diag_t = 2 * qb + (w >> 2);   // wave's straddling tile; > diag_t: fully masked

  __shared__ __align__(16) char smem[49152];
  char* Ksm = smem;                      // [64][128] bf16 swizzled
  char* Vsm = smem + 16384;              // V^T [128][64] bf16 swizzled
  char* Psm = smem + 32768 + (w << 11);  // per-wave [16][64] bf16

  const float qscale = 0.088388347648318447f * 1.4426950408889634f; // 1/sqrt(D)*log2(e)

  // Q fragments: lane holds Q[q0+w*16+lq][ks*32 + lg*8 + j], pre-scaled
  bf16x8 aq[4];
  {
    const int qrow = q0 + w * 16 + lq;
    const float* qp = Q + (size_t)qrow * RS + head * HDIM + lg * 8;
#pragma unroll
    for (int ks = 0; ks < 4; ++ks) {
      float4 v0 = *(const float4*)(qp + ks * 32);
      float4 v1 = *(const float4*)(qp + ks * 32 + 4);
      bf16x8 a;
      a[0] = (__bf16)(v0.x * qscale); a[1] = (__bf16)(v0.y * qscale);
      a[2] = (__bf16)(v0.z * qscale); a[3] = (__bf16)(v0.w * qscale);
      a[4] = (__bf16)(v1.x * qscale); a[5] = (__bf16)(v1.y * qscale);
      a[6] = (__bf16)(v1.z * qscale); a[7] = (__bf16)(v1.w * qscale);
      aq[ks] = a;
    }
  }

  f32x4 accO[8];
#pragma unroll
  for (int i = 0; i < 8; ++i) accO[i] = (f32x4){0.f, 0.f, 0.f, 0.f};
  float m_run[4] = {-1e30f, -1e30f, -1e30f, -1e30f};
  float l_run[4] = {0.f, 0.f, 0.f, 0.f};
  const int qrow_base = q0 + w * 16 + lg * 4;

  const char* kbase = wsK + (size_t)head * NTILES * TILE_BYTES;
  const char* vbase = wsV + (size_t)head * NTILES * TILE_BYTES;
  const int   q4    = (w & 3) * 4096;      // this wave's quarter of its tile
  const bool  doK   = (w < 4);

  for (int t = 0; t < ntile; ++t) {
    __syncthreads();   // all reads of previous tile complete
    {
      const char* src = (doK ? kbase : vbase) + (size_t)t * TILE_BYTES + q4 + lane * 16;
      char* dst = (doK ? Ksm : Vsm) + q4;
#pragma unroll
      for (int i = 0; i < 4; ++i) gld16(src + i * 1024, dst + i * 1024);
    }
    __syncthreads();   // barrier drains vmcnt -> staged tile visible

    if (t > diag_t) continue;   // fully masked for this wave (barrier counts still match)

    // ---- S = Q K^T ----
    f32x4 accS[4];
#pragma unroll
    for (int nt = 0; nt < 4; ++nt) {
      f32x4 s = (f32x4){0.f, 0.f, 0.f, 0.f};
      const int krow = nt * 16 + lq;
#pragma unroll
      for (int ks = 0; ks < 4; ++ks) {
        const uint32_t byte = (uint32_t)(krow * 256 + ks * 64 + lg * 16) ^
                              (uint32_t)((krow & 7) << 4);
        bf16x8 bk = *(const bf16x8*)(Ksm + byte);
        s = __builtin_amdgcn_mfma_f32_16x16x32_bf16(aq[ks], bk, s, 0, 0, 0);
      }
      accS[nt] = s;
    }

    // ---- causal mask (straddling tile only) + row max ----
    float mloc[4] = {-1e30f, -1e30f, -1e30f, -1e30f};
    if (t == diag_t) {
      const int kv0 = t * KVBLK;
#pragma unroll
      for (int nt = 0; nt < 4; ++nt) {
        const int keyg = kv0 + nt * 16 + lq;
#pragma unroll
        for (int j = 0; j < 4; ++j) {
          float s = accS[nt][j];
          s = (keyg <= qrow_base + j) ? s : -1e30f;
          accS[nt][j] = s;
          mloc[j] = fmaxf(mloc[j], s);
        }
      }
    } else {
#pragma unroll
      for (int nt = 0; nt < 4; ++nt)
#pragma unroll
        for (int j = 0; j < 4; ++j) mloc[j] = fmaxf(mloc[j], accS[nt][j]);
    }
#pragma unroll
    for (int off = 1; off < 16; off <<= 1) {
#pragma unroll
      for (int j = 0; j < 4; ++j)
        mloc[j] = fmaxf(mloc[j], __shfl_xor(mloc[j], off, 64));
    }

    // ---- defer-max (T13): only rescale when the new tile max exceeds m_run + 8 ----
    float need = 0.f;
#pragma unroll
    for (int j = 0; j < 4; ++j) need = fmaxf(need, mloc[j] - m_run[j]);
    if (__any(need > 8.0f)) {
      float alpha[4];
#pragma unroll
      for (int j = 0; j < 4; ++j) {
        const float mn = fmaxf(m_run[j], mloc[j]);
        alpha[j] = exp2f(m_run[j] - mn);
        m_run[j] = mn;
        l_run[j] *= alpha[j];
      }
#pragma unroll
      for (int dt = 0; dt < 8; ++dt)
#pragma unroll
        for (int j = 0; j < 4; ++j) accO[dt][j] *= alpha[j];
    }

    // ---- P = exp2(S - m_run), row sum ----
    float rsum[4] = {0.f, 0.f, 0.f, 0.f};
#pragma unroll
    for (int nt = 0; nt < 4; ++nt) {
#pragma unroll
      for (int j = 0; j < 4; ++j) {
        const float p = exp2f(accS[nt][j] - m_run[j]);
        accS[nt][j] = p;
        rsum[j] += p;
      }
    }
#pragma unroll
    for (int off = 1; off < 16; off <<= 1) {
#pragma unroll
      for (int j = 0; j < 4; ++j) rsum[j] += __shfl_xor(rsum[j], off, 64);
    }
#pragma unroll
    for (int j = 0; j < 4; ++j) l_run[j] += rsum[j];

    // ---- P -> wave-private LDS (swizzled) ----
#pragma unroll
    for (int j = 0; j < 4; ++j) {
      const int r = lg * 4 + j;
#pragma unroll
      for (int nt = 0; nt < 4; ++nt) {
        const int col = nt * 16 + lq;
        const uint32_t byte = (uint32_t)(r * 128 + col * 2) ^ (uint32_t)((r & 7) << 4);
        *(uint16_t*)(Psm + byte) = f2bf(accS[nt][j]);
      }
    }
    asm volatile("" ::: "memory");   // order P writes vs P reads (wave-private)

    // ---- O += P V ----
#pragma unroll
    for (int ks2 = 0; ks2 < 2; ++ks2) {
      const uint32_t ab = (uint32_t)(lq * 128 + ks2 * 64 + lg * 16) ^
                          (uint32_t)((lq & 7) << 4);
      bf16x8 ap = *(const bf16x8*)(Psm + ab);
#pragma unroll
      for (int dt = 0; dt < 8; ++dt) {
        const int vrow = dt * 16 + lq;
        const uint32_t bb = (uint32_t)(vrow * 128 + ks2 * 64 + lg * 16) ^
                            (uint32_t)((vrow & 7) << 4);
        bf16x8 bv = *(const bf16x8*)(Vsm + bb);
        accO[dt] = __builtin_amdgcn_mfma_f32_16x16x32_bf16(ap, bv, accO[dt], 0, 0, 0);
      }
    }
  }

  // ---- epilogue: O / l ----
#pragma unroll
  for (int j = 0; j < 4; ++j) {
    const float inv = 1.0f / l_run[j];
    float* op = O + (size_t)(qrow_base + j) * RS + head * HDIM + lq;
#pragma unroll
    for (int dt = 0; dt < 8; ++dt) op[dt * 16] = accO[dt][j] * inv;
  }
}

extern "C" void kernel_launch(void* const* d_in, const int* in_sizes, int n_in,
                              void* d_out, int out_size, void* d_ws, size_t ws_size,
                              hipStream_t stream) {
  const float* q = (const float*)d_in[0];
  const float* k = (const float*)d_in[1];
  const float* v = (const float*)d_in[2];
  float* o = (float*)d_out;
  char* wsK = (char*)d_ws;
  char* wsV = wsK + (size_t)NHEAD * NTILES * TILE_BYTES;
  hipLaunchKernelGGL(prepass_kernel, dim3(NHEAD * NTILES), dim3(256), 0, stream,
                     k, v, wsK, wsV);
  hipLaunchKernelGGL(fattn_main, dim3(512), dim3(512), 0, stream, q, wsK, wsV, o);
}

// Round 5
// 138.503 us; speedup vs baseline: 1.5471x; 1.0686x over previous
//
#include <hip/hip_runtime.h>
#include <hip/hip_bf16.h>
#include <stdint.h>

#define SEQ   2048
#define NHEAD 32
#define HDIM  128
#define RS    (NHEAD * HDIM)   // 4096 floats: row stride in (b,s,h,d) layout
#define KVBLK 64
#define QBLK  128
#define NTILES (SEQ / KVBLK)   // 32 kv tiles
#define TILE_BYTES 16384       // 64*128 bf16 per K tile / 128*64 per V^T tile

typedef float  f32x4  __attribute__((ext_vector_type(4)));
typedef __bf16 bf16x8 __attribute__((ext_vector_type(8)));

__device__ __forceinline__ unsigned short f2bf(float f) {
  unsigned u = __builtin_bit_cast(unsigned, f);
  u += 0x7fffu + ((u >> 16) & 1u);           // round-to-nearest-even
  return (unsigned short)(u >> 16);
}

__device__ __forceinline__ void gld16(const void* g, void* l) {
  // async global->LDS, 16B/lane; LDS dest is wave-uniform base (HW adds lane*16)
  __builtin_amdgcn_global_load_lds(
      (const __attribute__((address_space(1))) unsigned int*)g,
      (__attribute__((address_space(3))) unsigned int*)l, 16, 0, 0);
}

// ---------------- pre-pass: K -> bf16 swizzled tiles, V -> bf16 transposed swizzled tiles ----
__global__ __launch_bounds__(256) void prepass_kernel(
    const float* __restrict__ K, const float* __restrict__ V,
    char* __restrict__ wsK, char* __restrict__ wsV) {
  const int tid = threadIdx.x;
  const int t   = blockIdx.x & (NTILES - 1);
  const int h   = blockIdx.x >> 5;
  const int kv0 = t * KVBLK;
  char* kd = wsK + (size_t)(h * NTILES + t) * TILE_BYTES;
  char* vd = wsV + (size_t)(h * NTILES + t) * TILE_BYTES;

  // K: [64][128] bf16, byte = (kk*256 + c*16) ^ ((kk&7)<<4)
  {
    const int c  = tid & 15;    // d-chunk of 8 floats
    const int kr = tid >> 4;    // 0..15
#pragma unroll
    for (int ki = 0; ki < 4; ++ki) {
      const int kk = kr + ki * 16;
      const float* kp = K + (size_t)(kv0 + kk) * RS + h * HDIM + c * 8;
      float4 x0 = *(const float4*)kp;
      float4 x1 = *(const float4*)(kp + 4);
      uint32_t u0 = f2bf(x0.x) | ((uint32_t)f2bf(x0.y) << 16);
      uint32_t u1 = f2bf(x0.z) | ((uint32_t)f2bf(x0.w) << 16);
      uint32_t u2 = f2bf(x1.x) | ((uint32_t)f2bf(x1.y) << 16);
      uint32_t u3 = f2bf(x1.z) | ((uint32_t)f2bf(x1.w) << 16);
      const uint32_t byte = (uint32_t)(kk * 256 + c * 16) ^ (uint32_t)((kk & 7) << 4);
      *(uint4*)(kd + byte) = make_uint4(u0, u1, u2, u3);
    }
  }
  // V^T: [128][64] bf16, byte = (d*128 + kk*2) ^ ((d&7)<<4)
  {
    const int d0  = (tid & 31) * 4;   // 4 d values
    const int kk0 = (tid >> 5) * 8;   // 8 kk values
    float vv[8][4];
#pragma unroll
    for (int r = 0; r < 8; ++r) {
      const float* vp = V + (size_t)(kv0 + kk0 + r) * RS + h * HDIM + d0;
      float4 x = *(const float4*)vp;
      vv[r][0] = x.x; vv[r][1] = x.y; vv[r][2] = x.z; vv[r][3] = x.w;
    }
#pragma unroll
    for (int i = 0; i < 4; ++i) {
      const int d = d0 + i;
      uint32_t p0 = f2bf(vv[0][i]) | ((uint32_t)f2bf(vv[1][i]) << 16);
      uint32_t p1 = f2bf(vv[2][i]) | ((uint32_t)f2bf(vv[3][i]) << 16);
      uint32_t p2 = f2bf(vv[4][i]) | ((uint32_t)f2bf(vv[5][i]) << 16);
      uint32_t p3 = f2bf(vv[6][i]) | ((uint32_t)f2bf(vv[7][i]) << 16);
      const uint32_t byte = (uint32_t)(d * 128 + kk0 * 2) ^ (uint32_t)((d & 7) << 4);
      *(uint4*)(vd + byte) = make_uint4(p0, p1, p2, p3);
    }
  }
}

// ---------------- main: QBLK=128, 8 waves, dbuf K/V, EXPLICIT waitcnt drains ----
__global__ __launch_bounds__(512, 4) void fattn_main(
    const float* __restrict__ Q, const char* __restrict__ wsK,
    const char* __restrict__ wsV, float* __restrict__ O) {
  const int tid  = threadIdx.x;
  const int w    = tid >> 6;      // wave 0..7
  const int lane = tid & 63;
  const int lq   = lane & 15;
  const int lg   = lane >> 4;

  // XCD swizzle + complement pairing: (bid, bid+256) land on the same CU and
  // their qb values sum to 15 -> exactly 34 tile-iters per CU.
  const int bid  = blockIdx.x;          // 0..511
  const int b2   = bid & 255;
  const int vid  = (b2 & 7) * 32 + (b2 >> 3);   // XCD x gets heads 4x..4x+3
  const int head = vid >> 3;
  const int jj   = vid & 7;
  const int qb   = (bid < 256) ? (15 - jj) : jj;
  const int q0   = qb * QBLK;
  const int ntile  = 2 * qb + 2;
  const int diag_t = 2 * qb + (w >> 2);   // wave's straddling tile; > diag_t: fully masked

  __shared__ __align__(16) char smem[81920];
  char* KsmB = smem;                      // 2 x [64][128] bf16 swizzled
  char* VsmB = smem + 32768;              // 2 x V^T [128][64] bf16 swizzled
  char* Psm  = smem + 65536 + (w << 11);  // per-wave [16][64] bf16

  const float qscale = 0.088388347648318447f * 1.4426950408889634f; // 1/sqrt(D)*log2(e)

  // Q fragments: lane holds Q[q0+w*16+lq][ks*32 + lg*8 + j], pre-scaled
  bf16x8 aq[4];
  {
    const int qrow = q0 + w * 16 + lq;
    const float* qp = Q + (size_t)qrow * RS + head * HDIM + lg * 8;
#pragma unroll
    for (int ks = 0; ks < 4; ++ks) {
      float4 v0 = *(const float4*)(qp + ks * 32);
      float4 v1 = *(const float4*)(qp + ks * 32 + 4);
      bf16x8 a;
      a[0] = (__bf16)(v0.x * qscale); a[1] = (__bf16)(v0.y * qscale);
      a[2] = (__bf16)(v0.z * qscale); a[3] = (__bf16)(v0.w * qscale);
      a[4] = (__bf16)(v1.x * qscale); a[5] = (__bf16)(v1.y * qscale);
      a[6] = (__bf16)(v1.z * qscale); a[7] = (__bf16)(v1.w * qscale);
      aq[ks] = a;
    }
  }

  // ones fragment: B-operand of the l-accumulation MFMA
  bf16x8 ones;
#pragma unroll
  for (int i = 0; i < 8; ++i) ones[i] = (__bf16)1.0f;

  f32x4 accO[8];
#pragma unroll
  for (int i = 0; i < 8; ++i) accO[i] = (f32x4){0.f, 0.f, 0.f, 0.f};
  f32x4 accL = (f32x4){0.f, 0.f, 0.f, 0.f};   // row-sums via MFMA (same row layout as accO)
  float m_run[4] = {-1e30f, -1e30f, -1e30f, -1e30f};
  const int qrow_base = q0 + w * 16 + lg * 4;

  const char* kbase = wsK + (size_t)head * NTILES * TILE_BYTES;
  const char* vbase = wsV + (size_t)head * NTILES * TILE_BYTES;
  const int   q4    = (w & 3) * 4096;      // this wave's quarter of its tile
  const bool  doK   = (w < 4);
  const char* sbase = (doK ? kbase : vbase);

  auto stage = [&](int buf, int t) {
    const char* src = sbase + (size_t)t * TILE_BYTES + q4 + lane * 16;
    char* dst = (doK ? KsmB : VsmB) + buf * TILE_BYTES + q4;
#pragma unroll
    for (int i = 0; i < 4; ++i) gld16(src + i * 1024, dst + i * 1024);
  };

  stage(0, 0);
  asm volatile("s_waitcnt vmcnt(0)" ::: "memory");   // explicit drain: tile 0 resident
  __builtin_amdgcn_sched_barrier(0);
  __syncthreads();

  for (int t = 0; t < ntile; ++t) {
    const int cur = t & 1;
    if (t + 1 < ntile) stage(cur ^ 1, t + 1);   // async prefetch; drained before bottom barrier

    if (t <= diag_t) {
      const char* Kc = KsmB + cur * TILE_BYTES;
      const char* Vc = VsmB + cur * TILE_BYTES;

      // ---- S = Q K^T ----
      f32x4 accS[4];
#pragma unroll
      for (int nt = 0; nt < 4; ++nt) {
        f32x4 s = (f32x4){0.f, 0.f, 0.f, 0.f};
        const int krow = nt * 16 + lq;
#pragma unroll
        for (int ks = 0; ks < 4; ++ks) {
          const uint32_t byte = (uint32_t)(krow * 256 + ks * 64 + lg * 16) ^
                                (uint32_t)((krow & 7) << 4);
          bf16x8 bk = *(const bf16x8*)(Kc + byte);
          s = __builtin_amdgcn_mfma_f32_16x16x32_bf16(aq[ks], bk, s, 0, 0, 0);
        }
        accS[nt] = s;
      }

      // ---- causal mask (straddling tile only) + row max ----
      float mloc[4] = {-1e30f, -1e30f, -1e30f, -1e30f};
      if (t == diag_t) {
        const int kv0 = t * KVBLK;
#pragma unroll
        for (int nt = 0; nt < 4; ++nt) {
          const int keyg = kv0 + nt * 16 + lq;
#pragma unroll
          for (int j = 0; j < 4; ++j) {
            float s = accS[nt][j];
            s = (keyg <= qrow_base + j) ? s : -1e30f;
            accS[nt][j] = s;
            mloc[j] = fmaxf(mloc[j], s);
          }
        }
      } else {
#pragma unroll
        for (int nt = 0; nt < 4; ++nt)
#pragma unroll
          for (int j = 0; j < 4; ++j) mloc[j] = fmaxf(mloc[j], accS[nt][j]);
      }
#pragma unroll
      for (int off = 1; off < 16; off <<= 1) {
#pragma unroll
        for (int j = 0; j < 4; ++j)
          mloc[j] = fmaxf(mloc[j], __shfl_xor(mloc[j], off, 64));
      }

      // ---- defer-max (T13): rescale only when tile max exceeds m_run + 8 ----
      float need = 0.f;
#pragma unroll
      for (int j = 0; j < 4; ++j) need = fmaxf(need, mloc[j] - m_run[j]);
      if (__any(need > 8.0f)) {
        float alpha[4];
#pragma unroll
        for (int j = 0; j < 4; ++j) {
          const float mn = fmaxf(m_run[j], mloc[j]);
          alpha[j] = exp2f(m_run[j] - mn);
          m_run[j] = mn;
          accL[j] *= alpha[j];
        }
#pragma unroll
        for (int dt = 0; dt < 8; ++dt)
#pragma unroll
          for (int j = 0; j < 4; ++j) accO[dt][j] *= alpha[j];
      }

      // ---- P = exp2(S - m_run) (row sum comes from the ones-MFMA below) ----
#pragma unroll
      for (int nt = 0; nt < 4; ++nt)
#pragma unroll
        for (int j = 0; j < 4; ++j)
          accS[nt][j] = exp2f(accS[nt][j] - m_run[j]);

      // ---- P -> wave-private LDS (swizzled) ----
#pragma unroll
      for (int j = 0; j < 4; ++j) {
        const int r = lg * 4 + j;
#pragma unroll
        for (int nt = 0; nt < 4; ++nt) {
          const int col = nt * 16 + lq;
          const uint32_t byte = (uint32_t)(r * 128 + col * 2) ^ (uint32_t)((r & 7) << 4);
          *(uint16_t*)(Psm + byte) = f2bf(accS[nt][j]);
        }
      }
      asm volatile("s_waitcnt lgkmcnt(0)" ::: "memory");  // P writes retired before reads
      __builtin_amdgcn_sched_barrier(0);

      // ---- O += P V ; accL += P * ones (row-sum) ----
#pragma unroll
      for (int ks2 = 0; ks2 < 2; ++ks2) {
        const uint32_t ab = (uint32_t)(lq * 128 + ks2 * 64 + lg * 16) ^
                            (uint32_t)((lq & 7) << 4);
        bf16x8 ap = *(const bf16x8*)(Psm + ab);
        accL = __builtin_amdgcn_mfma_f32_16x16x32_bf16(ap, ones, accL, 0, 0, 0);
#pragma unroll
        for (int dt = 0; dt < 8; ++dt) {
          const int vrow = dt * 16 + lq;
          const uint32_t bb = (uint32_t)(vrow * 128 + ks2 * 64 + lg * 16) ^
                              (uint32_t)((vrow & 7) << 4);
          bf16x8 bv = *(const bf16x8*)(Vc + bb);
          accO[dt] = __builtin_amdgcn_mfma_f32_16x16x32_bf16(ap, bv, accO[dt], 0, 0, 0);
        }
      }
    }

    // explicit drain: prefetch landed (vmcnt) AND all LDS reads retired (lgkmcnt)
    asm volatile("s_waitcnt vmcnt(0) lgkmcnt(0)" ::: "memory");
    __builtin_amdgcn_sched_barrier(0);
    __syncthreads();
  }

  // ---- epilogue: O / l ----
#pragma unroll
  for (int j = 0; j < 4; ++j) {
    const float inv = 1.0f / accL[j];
    float* op = O + (size_t)(qrow_base + j) * RS + head * HDIM + lq;
#pragma unroll
    for (int dt = 0; dt < 8; ++dt) op[dt * 16] = accO[dt][j] * inv;
  }
}

extern "C" void kernel_launch(void* const* d_in, const int* in_sizes, int n_in,
                              void* d_out, int out_size, void* d_ws, size_t ws_size,
                              hipStream_t stream) {
  const float* q = (const float*)d_in[0];
  const float* k = (const float*)d_in[1];
  const float* v = (const float*)d_in[2];
  float* o = (float*)d_out;
  char* wsK = (char*)d_ws;
  char* wsV = wsK + (size_t)NHEAD * NTILES * TILE_BYTES;
  hipLaunchKernelGGL(prepass_kernel, dim3(NHEAD * NTILES), dim3(256), 0, stream,
                     k, v, wsK, wsV);
  hipLaunchKernelGGL(fattn_main, dim3(512), dim3(512), 0, stream, q, wsK, wsV, o);
}

// Round 6
// 88.424 us; speedup vs baseline: 2.4232x; 1.5663x over previous
//
#include <hip/hip_runtime.h>
#include <hip/hip_bf16.h>
#include <stdint.h>

#define SEQ   2048
#define NHEAD 32
#define HDIM  128
#define RS    (NHEAD * HDIM)   // 4096 floats: row stride in (b,s,h,d) layout
#define KVBLK 64
#define QBLK  128
#define NTILES (SEQ / KVBLK)   // 32 kv tiles
#define TILE_BYTES 16384       // 64*128 bf16 per K tile / 128*64 per V^T tile

typedef float  f32x16 __attribute__((ext_vector_type(16)));
typedef __bf16 bf16x8 __attribute__((ext_vector_type(8)));
typedef uint32_t u32;

__device__ __forceinline__ unsigned short f2bf(float f) {
  unsigned u = __builtin_bit_cast(unsigned, f);
  u += 0x7fffu + ((u >> 16) & 1u);           // round-to-nearest-even
  return (unsigned short)(u >> 16);
}

__device__ __forceinline__ u32 packbf(float a, float b) {
  __bf16 x = (__bf16)a, y = (__bf16)b;       // compiler emits v_cvt (RNE)
  unsigned short ux = __builtin_bit_cast(unsigned short, x);
  unsigned short uy = __builtin_bit_cast(unsigned short, y);
  return (u32)ux | ((u32)uy << 16);
}

__device__ __forceinline__ void gld16(const void* g, void* l) {
  // async global->LDS, 16B/lane; LDS dest is wave-uniform base (HW adds lane*16)
  __builtin_amdgcn_global_load_lds(
      (const __attribute__((address_space(1))) unsigned int*)g,
      (__attribute__((address_space(3))) unsigned int*)l, 16, 0, 0);
}

// ---------------- pre-pass ----------------
// K image:  byte(key,d) = key*256 + ((d*2) ^ ((key&15)<<4))   [16-slot swizzle, 256B rows]
// V^T image: byte(d,kk) = d*128 + ((kk*2) ^ ((d&7)<<4))       [8-slot swizzle, 128B rows]
__global__ __launch_bounds__(256) void prepass_kernel(
    const float* __restrict__ K, const float* __restrict__ V,
    char* __restrict__ wsK, char* __restrict__ wsV) {
  const int tid = threadIdx.x;
  const int t   = blockIdx.x & (NTILES - 1);
  const int h   = blockIdx.x >> 5;
  const int kv0 = t * KVBLK;
  char* kd = wsK + (size_t)(h * NTILES + t) * TILE_BYTES;
  char* vd = wsV + (size_t)(h * NTILES + t) * TILE_BYTES;

  // K tile
  {
    const int c  = tid & 15;    // d-chunk of 8 floats
    const int kr = tid >> 4;    // 0..15
#pragma unroll
    for (int ki = 0; ki < 4; ++ki) {
      const int kk = kr + ki * 16;
      const float* kp = K + (size_t)(kv0 + kk) * RS + h * HDIM + c * 8;
      float4 x0 = *(const float4*)kp;
      float4 x1 = *(const float4*)(kp + 4);
      uint32_t u0 = f2bf(x0.x) | ((uint32_t)f2bf(x0.y) << 16);
      uint32_t u1 = f2bf(x0.z) | ((uint32_t)f2bf(x0.w) << 16);
      uint32_t u2 = f2bf(x1.x) | ((uint32_t)f2bf(x1.y) << 16);
      uint32_t u3 = f2bf(x1.z) | ((uint32_t)f2bf(x1.w) << 16);
      const uint32_t byte = (uint32_t)(kk * 256) + (((uint32_t)(c * 16)) ^ (uint32_t)((kk & 15) << 4));
      *(uint4*)(kd + byte) = make_uint4(u0, u1, u2, u3);
    }
  }
  // V^T tile
  {
    const int d0  = (tid & 31) * 4;   // 4 d values
    const int kk0 = (tid >> 5) * 8;   // 8 kk values
    float vv[8][4];
#pragma unroll
    for (int r = 0; r < 8; ++r) {
      const float* vp = V + (size_t)(kv0 + kk0 + r) * RS + h * HDIM + d0;
      float4 x = *(const float4*)vp;
      vv[r][0] = x.x; vv[r][1] = x.y; vv[r][2] = x.z; vv[r][3] = x.w;
    }
#pragma unroll
    for (int i = 0; i < 4; ++i) {
      const int d = d0 + i;
      uint32_t p0 = f2bf(vv[0][i]) | ((uint32_t)f2bf(vv[1][i]) << 16);
      uint32_t p1 = f2bf(vv[2][i]) | ((uint32_t)f2bf(vv[3][i]) << 16);
      uint32_t p2 = f2bf(vv[4][i]) | ((uint32_t)f2bf(vv[5][i]) << 16);
      uint32_t p3 = f2bf(vv[6][i]) | ((uint32_t)f2bf(vv[7][i]) << 16);
      const uint32_t byte = (uint32_t)(d * 128) + (((uint32_t)(kk0 * 2)) ^ (uint32_t)((d & 7) << 4));
      *(uint4*)(vd + byte) = make_uint4(p0, p1, p2, p3);
    }
  }
}

// ---------------- main: 4 waves x 32 q-rows, 32x32 MFMA, swapped QK^T, in-register softmax ----
__global__ __launch_bounds__(256, 2) void fattn_main(
    const float* __restrict__ Q, const char* __restrict__ wsK,
    const char* __restrict__ wsV, float* __restrict__ O) {
  const int tid  = threadIdx.x;
  const int w    = tid >> 6;      // wave 0..3
  const int lane = tid & 63;
  const int n    = lane & 31;     // q-row (QK D-col) / d-col (PV D-col)
  const int hh   = lane >> 5;     // lane half

  // XCD swizzle + complement pairing: (bid, bid+256) land on the same CU and
  // their qb values sum to 15 -> exactly 34 kv-tile-iters per CU.
  const int bid  = blockIdx.x;          // 0..511
  const int b2   = bid & 255;
  const int vid  = (b2 & 7) * 32 + (b2 >> 3);
  const int head = vid >> 3;
  const int jj   = vid & 7;
  const int qb   = (bid < 256) ? (15 - jj) : jj;
  const int q0   = qb * QBLK;
  const int ntile  = 2 * qb + 2;
  const int diag_t = 2 * qb + (w >> 1);   // wave's straddling tile

  __shared__ __align__(16) char smem[65536];   // 2 x (16KB K + 16KB V^T)
  auto Kbuf = [&](int b) { return smem + b * 32768; };
  auto Vbuf = [&](int b) { return smem + b * 32768 + 16384; };

  const float qscale = 0.088388347648318447f * 1.4426950408889634f; // 1/sqrt(D)*log2(e)

  const int qrow = q0 + w * 32 + n;   // this lane's q-row (lane pairs share it)

  // Q B-fragments: bq[ks] holds Q[qrow][ks*16 + hh*8 + j] * qscale
  bf16x8 bq[8];
  {
    const float* qp = Q + (size_t)qrow * RS + head * HDIM + hh * 8;
#pragma unroll
    for (int ks = 0; ks < 8; ++ks) {
      float4 v0 = *(const float4*)(qp + ks * 16);
      float4 v1 = *(const float4*)(qp + ks * 16 + 4);
      bf16x8 a;
      a[0] = (__bf16)(v0.x * qscale); a[1] = (__bf16)(v0.y * qscale);
      a[2] = (__bf16)(v0.z * qscale); a[3] = (__bf16)(v0.w * qscale);
      a[4] = (__bf16)(v1.x * qscale); a[5] = (__bf16)(v1.y * qscale);
      a[6] = (__bf16)(v1.z * qscale); a[7] = (__bf16)(v1.w * qscale);
      bq[ks] = a;
    }
  }

  f32x16 accO[4];
#pragma unroll
  for (int i = 0; i < 4; ++i) accO[i] = (f32x16)(0.f);
  float m_run  = -1e30f;
  float l_part = 0.f;     // own-half partial row sum

  const char* kbase = wsK + (size_t)head * NTILES * TILE_BYTES;
  const char* vbase = wsV + (size_t)head * NTILES * TILE_BYTES;
  const bool  doK   = (w < 2);
  const char* sbase = doK ? kbase : vbase;
  const int   half  = (w & 1) * 8192;

  auto stage = [&](int buf, int t) {
    const char* src = sbase + (size_t)t * TILE_BYTES + half + lane * 16;
    char* dst = (doK ? Kbuf(buf) : Vbuf(buf)) + half;
#pragma unroll
    for (int i = 0; i < 8; ++i) gld16(src + i * 1024, dst + i * 1024);
  };

  stage(0, 0);
  asm volatile("s_waitcnt vmcnt(0)" ::: "memory");
  __builtin_amdgcn_sched_barrier(0);
  __syncthreads();

  for (int t = 0; t < ntile; ++t) {
    const int cur = t & 1;
    if (t + 1 < ntile) stage(cur ^ 1, t + 1);   // async prefetch

    if (t <= diag_t) {
      const char* Kc = Kbuf(cur);
      const char* Vc = Vbuf(cur);

      // ---- S^T = K Q^T : sc[kt][r] = S[key][qrow], key = kv0 + kt*32 + (r&3)+8*(r>>2)+4*hh ----
      f32x16 sc[2];
      __builtin_amdgcn_s_setprio(1);
#pragma unroll
      for (int kt = 0; kt < 2; ++kt) {
        f32x16 acc = (f32x16)(0.f);
        const int key = kt * 32 + n;
        const uint32_t rowb = (uint32_t)(key * 256);
        const uint32_t swz  = (uint32_t)((key & 15) << 4);
#pragma unroll
        for (int ks = 0; ks < 8; ++ks) {
          const uint32_t byte = rowb + (((uint32_t)(ks * 32 + hh * 16)) ^ swz);
          bf16x8 kf = *(const bf16x8*)(Kc + byte);
          acc = __builtin_amdgcn_mfma_f32_32x32x16_bf16(kf, bq[ks], acc, 0, 0, 0);
        }
        sc[kt] = acc;
      }
      __builtin_amdgcn_s_setprio(0);

      // ---- causal mask (straddling tile only) ----
      if (t == diag_t) {
        const int kv0 = t * KVBLK;
#pragma unroll
        for (int kt = 0; kt < 2; ++kt)
#pragma unroll
          for (int r = 0; r < 16; ++r) {
            const int keyg = kv0 + kt * 32 + (r & 3) + 8 * (r >> 2) + 4 * hh;
            if (keyg > qrow) sc[kt][r] = -1e30f;
          }
      }

      // ---- row max: 31 in-lane + 1 cross-half swap ----
      float mx = -1e30f;
#pragma unroll
      for (int kt = 0; kt < 2; ++kt)
#pragma unroll
        for (int r = 0; r < 16; ++r) mx = fmaxf(mx, sc[kt][r]);
      mx = fmaxf(mx, __shfl_xor(mx, 32, 64));

      // ---- defer-max (T13, log2-domain THR=11): rare rescale ----
      if (__any(mx - m_run > 11.0f)) {
        const float mn = fmaxf(m_run, mx);
        const float al = exp2f(m_run - mn);
        m_run = mn;
        l_part *= al;
#pragma unroll
        for (int r = 0; r < 16; ++r) {
          const float ar = __shfl(al, (r & 3) + 8 * (r >> 2) + 4 * hh, 64);
#pragma unroll
          for (int nt = 0; nt < 4; ++nt) accO[nt][r] *= ar;
        }
      }

      // ---- P = exp2(S - m_run); own-half row sum ----
      float ls = 0.f;
#pragma unroll
      for (int kt = 0; kt < 2; ++kt)
#pragma unroll
        for (int r = 0; r < 16; ++r) {
          const float p = exp2f(sc[kt][r] - m_run);
          sc[kt][r] = p;
          ls += p;
        }
      l_part += ls;

      // ---- pack P to bf16 pairs: ua[kt][i] = keys {8i+4hh, +1}, ub = {+2, +3} ----
      u32 ua[2][4], ub[2][4];
#pragma unroll
      for (int kt = 0; kt < 2; ++kt)
#pragma unroll
        for (int i = 0; i < 4; ++i) {
          ua[kt][i] = packbf(sc[kt][4 * i],     sc[kt][4 * i + 1]);
          ub[kt][i] = packbf(sc[kt][4 * i + 2], sc[kt][4 * i + 3]);
        }

      // ---- cross-half exchange: each half sends what the partner needs ----
      u32 ra[2][2], rb[2][2];
#pragma unroll
      for (int kt = 0; kt < 2; ++kt)
#pragma unroll
        for (int q = 0; q < 2; ++q) {
          ra[kt][q] = __shfl_xor(hh ? ua[kt][2 * q] : ua[kt][2 * q + 1], 32, 64);
          rb[kt][q] = __shfl_xor(hh ? ub[kt][2 * q] : ub[kt][2 * q + 1], 32, 64);
        }

      // ---- O += P V : 4 k-steps x 4 d-tiles ----
      __builtin_amdgcn_s_setprio(1);
#pragma unroll
      for (int s = 0; s < 4; ++s) {
        const int kt = s >> 1, q = s & 1;
        u32 af32[4];
        af32[0] = hh ? ra[kt][q] : ua[kt][2 * q];
        af32[1] = hh ? rb[kt][q] : ub[kt][2 * q];
        af32[2] = hh ? ua[kt][2 * q + 1] : ra[kt][q];
        af32[3] = hh ? ub[kt][2 * q + 1] : rb[kt][q];
        bf16x8 af = __builtin_bit_cast(bf16x8, *(uint4*)af32);
#pragma unroll
        for (int nt = 0; nt < 4; ++nt) {
          const int d = nt * 32 + n;
          const uint32_t byte = (uint32_t)(d * 128) +
              (((uint32_t)(s * 32 + hh * 16)) ^ (uint32_t)((d & 7) << 4));
          bf16x8 vf = *(const bf16x8*)(Vc + byte);
          accO[nt] = __builtin_amdgcn_mfma_f32_32x32x16_bf16(af, vf, accO[nt], 0, 0, 0);
        }
      }
      __builtin_amdgcn_s_setprio(0);
    }

    asm volatile("s_waitcnt vmcnt(0) lgkmcnt(0)" ::: "memory");
    __builtin_amdgcn_sched_barrier(0);
    __syncthreads();
  }

  // ---- epilogue: combine halves, O / l ----
  const float lf  = l_part + __shfl_xor(l_part, 32, 64);
  const float inv = 1.0f / lf;          // for own q-row (lane n)
  float* ob = O + (size_t)(q0 + w * 32) * RS + head * HDIM;
#pragma unroll
  for (int r = 0; r < 16; ++r) {
    const int m = (r & 3) + 8 * (r >> 2) + 4 * hh;
    const float im = __shfl(inv, m, 64);
#pragma unroll
    for (int nt = 0; nt < 4; ++nt)
      ob[(size_t)m * RS + nt * 32 + n] = accO[nt][r] * im;
  }
}

extern "C" void kernel_launch(void* const* d_in, const int* in_sizes, int n_in,
                              void* d_out, int out_size, void* d_ws, size_t ws_size,
                              hipStream_t stream) {
  const float* q = (const float*)d_in[0];
  const float* k = (const float*)d_in[1];
  const float* v = (const float*)d_in[2];
  float* o = (float*)d_out;
  char* wsK = (char*)d_ws;
  char* wsV = wsK + (size_t)NHEAD * NTILES * TILE_BYTES;
  hipLaunchKernelGGL(prepass_kernel, dim3(NHEAD * NTILES), dim3(256), 0, stream,
                     k, v, wsK, wsV);
  hipLaunchKernelGGL(fattn_main, dim3(512), dim3(256), 0, stream, q, wsK, wsV, o);
}